// Round 5
// baseline (338.629 us; speedup 1.0000x reference)
//
#include <hip/hip_runtime.h>
#include <math.h>

#define NN 4096   // nodes

using f32x4  = __attribute__((ext_vector_type(4))) float;
using bf16x4 = __attribute__((ext_vector_type(4))) __bf16;
using bf16x8 = __attribute__((ext_vector_type(8))) __bf16;

// ---------------- async global->LDS staging (16B, XOR-swizzled chunks) ----------------
// Row f of 64 bf16 = 8 chunks of 8; LDS slot s of row f holds global chunk s^(f&7).
template<int FH, int NTH>
__device__ __forceinline__ void stage_tile(const __bf16* __restrict__ hgp,
                                           __bf16* dst, int tid) {
#pragma unroll
    for (int it = 0; it < FH * 8 / NTH; it++) {
        int c = tid + it * NTH;
        int f = c >> 3, sl = c & 7;
        int g = sl ^ (f & 7);
        __builtin_amdgcn_global_load_lds(
            (const __attribute__((address_space(1))) void*)(hgp + (size_t)f * NN + g * 8),
            (__attribute__((address_space(3))) void*)(dst + (size_t)c * 8), 16, 0, 0);
    }
}

__device__ __forceinline__ void stage_g(const __bf16* __restrict__ base, int ldk,
                                        __bf16* dst, int tid) {
#pragma unroll
    for (int it = 0; it < 2; it++) {
        int c = tid + it * 256;
        int f = c >> 3, sl = c & 7;
        int g = sl ^ (f & 7);
        __builtin_amdgcn_global_load_lds(
            (const __attribute__((address_space(1))) void*)(base + (size_t)f * ldk + g * 8),
            (__attribute__((address_space(3))) void*)(dst + (size_t)c * 8), 16, 0, 0);
    }
}

// ---------------- adjacency -> bitmask ----------------
__global__ void pack_adj_kernel(const int* __restrict__ adj,
                                unsigned long long* __restrict__ bits) {
    int gw = (blockIdx.x * blockDim.x + threadIdx.x) >> 6;
    int lane = threadIdx.x & 63;
    int v = adj[(size_t)gw * 64 + lane];
    unsigned long long m = __ballot(v > 0);
    if (lane == 0) bits[gw] = m;
}

// ---------------- prepack: W_h -> Bt1[n=512][k=512] bf16, W_o -> Bt2[n=64][k=512] ----
__global__ void prepack_kernel(const float* __restrict__ W_h, const float* __restrict__ b_h,
                               const float* __restrict__ W_o,
                               __bf16* __restrict__ Bt1, float* __restrict__ biasp,
                               __bf16* __restrict__ Bt2) {
    int idx = blockIdx.x * 256 + threadIdx.x;   // 512*512
    {
        int n = idx >> 9, k = idx & 511;
        int h = n >> 7, f = n & 127;
        Bt1[idx] = (__bf16)W_h[(size_t)h * 512 * 128 + k * 128 + f];
    }
    if (idx < 64 * 512) {
        int n = idx >> 9, k = idx & 511;
        Bt2[idx] = (__bf16)W_o[k * 64 + n];
    }
    if (idx < 512) biasp[idx] = b_h[idx];
}

// ---------------- fp32 -> bf16 cast ----------------
__global__ void cast_bf16_kernel(const float* __restrict__ src, __bf16* __restrict__ dst) {
    int i = blockIdx.x * 256 + threadIdx.x;
    f32x4 v = *(const f32x4*)(src + (size_t)i * 4);
    bf16x4 o;
#pragma unroll
    for (int q = 0; q < 4; q++) o[q] = (__bf16)v[q];
    *(bf16x4*)(dst + (size_t)i * 4) = o;
}

// ---------------- fused bf16 MFMA GEMM ----------------
// Ht[col][row] = bf16( (A @ Bt^T)[row][col] + bias[col] )   (transposed store)
// s1[head][row] += sum_col h*a1[col], s2 likewise (fp32 atomics; head = bn>>7)
__global__ __launch_bounds__(256) void gemm_fused_kernel(
    const __bf16* __restrict__ A, const __bf16* __restrict__ Bt,
    const float* __restrict__ bias,
    const float* __restrict__ a1, const float* __restrict__ a2,
    __bf16* __restrict__ Ht, float* __restrict__ s1, float* __restrict__ s2,
    int M, int N, int K)
{
    __shared__ __attribute__((aligned(16))) __bf16 As[2][64 * 64];
    __shared__ __attribute__((aligned(16))) __bf16 Bs[2][64 * 64];
    const int tid = threadIdx.x, w = tid >> 6, l = tid & 63, o = l >> 4, rl = l & 15;
    const int bm = blockIdx.y * 64, bn = blockIdx.x * 64;
    f32x4 acc[4] = {};
    stage_g(A + (size_t)bm * K, K, &As[0][0], tid);
    stage_g(Bt + (size_t)bn * K, K, &Bs[0][0], tid);
    const int KB = K / 64;
    for (int kb = 0; kb < KB; kb++) {
        int b = kb & 1;
        __syncthreads();
        if (kb + 1 < KB) {
            stage_g(A + (size_t)bm * K + (kb + 1) * 64, K, &As[b ^ 1][0], tid);
            stage_g(Bt + (size_t)bn * K + (kb + 1) * 64, K, &Bs[b ^ 1][0], tid);
        }
#pragma unroll
        for (int kt = 0; kt < 2; kt++) {
            int ra = w * 16 + rl;
            int cg = kt * 4 + o;
            bf16x8 af = *(const bf16x8*)(&As[b][(ra * 8 + (cg ^ (ra & 7))) * 8]);
#pragma unroll
            for (int nt = 0; nt < 4; nt++) {
                int rb = nt * 16 + rl;
                bf16x8 bfr = *(const bf16x8*)(&Bs[b][(rb * 8 + (cg ^ (rb & 7))) * 8]);
                acc[nt] = __builtin_amdgcn_mfma_f32_16x16x32_bf16(af, bfr, acc[nt], 0, 0, 0);
            }
        }
    }
    const int head = bn >> 7;
    const int row_base = bm + w * 16 + o * 4;
    float p1[4] = {0.f, 0.f, 0.f, 0.f}, p2[4] = {0.f, 0.f, 0.f, 0.f};
#pragma unroll
    for (int nt = 0; nt < 4; nt++) {
        int col = bn + nt * 16 + rl;
        float bv = bias[col];
        float a1v = a1[col], a2v = a2[col];
        bf16x4 hv;
#pragma unroll
        for (int r4 = 0; r4 < 4; r4++) {
            float h = acc[nt][r4] + bv;
            hv[r4] = (__bf16)h;
            p1[r4] += h * a1v;
            p2[r4] += h * a2v;
        }
        *(bf16x4*)(Ht + (size_t)col * M + row_base) = hv;
    }
#pragma unroll
    for (int r4 = 0; r4 < 4; r4++)
#pragma unroll
        for (int off = 1; off < 16; off <<= 1) {
            p1[r4] += __shfl_xor(p1[r4], off, 64);
            p2[r4] += __shfl_xor(p2[r4], off, 64);
        }
    if (rl == 0)
#pragma unroll
        for (int r4 = 0; r4 < 4; r4++) {
            atomicAdd(&s1[(size_t)head * M + row_base + r4], p1[r4]);
            atomicAdd(&s2[(size_t)head * M + row_base + r4], p2[r4]);
        }
}

// ---------------- attn prep: s2max + Bv/Dv exp tables per head ----------------
// Bv[j]=exp(s2_j - s2max) <= 1,  Dv[j]=exp(0.2(s2_j - s2max)) <= 1.
// One block per head.
__global__ void attn_prep_kernel(const float* __restrict__ s2_all,
                                 float* __restrict__ s2max_all,
                                 float* __restrict__ BD) {
    const int head = blockIdx.x;
    const float* s2 = s2_all + (size_t)head * NN;
    const int t = threadIdx.x;
    float m = -INFINITY;
    for (int i = t; i < NN; i += 256) m = fmaxf(m, s2[i]);
#pragma unroll
    for (int off = 1; off < 64; off <<= 1) m = fmaxf(m, __shfl_xor(m, off, 64));
    __shared__ float red[4];
    if ((t & 63) == 0) red[t >> 6] = m;
    __syncthreads();
    float smax = fmaxf(fmaxf(red[0], red[1]), fmaxf(red[2], red[3]));
    if (t == 0) s2max_all[head] = smax;
    float* Bv = BD + (size_t)head * 2 * NN;
    float* Dv = Bv + NN;
    for (int i = t; i < NN; i += 256) {
        float d = s2[i] - smax;
        Bv[i] = __expf(d);
        Dv[i] = __expf(0.2f * d);
    }
}

// ---------------- MFMA attention: in-register A-frags, separable exp ----------------
// p_ij = mask * ( s1_i+s2_j>=0 ? A_i*Bv_j : C_i*Dv_j ),  all factors <= 1.
//   A_i=exp(z-m), C_i=exp(0.2z-m), m=lrelu(z), z=s1_i+s2max; test via Bv_j >= exp(-z).
// Block = WAVES waves; wave owns 32 rows (2 m-tiles), loops ALL n-tiles -> P stays
// in registers, each B-frag read feeds 2 MFMAs, ONE barrier per j-tile
// (orders prev-iter hbuf reads before overwrite + drains this tile's DMA).
// Global-bound m => j-split partials add exactly; combine kernels finish.
template<int FH, int JSPLIT, int WAVES>
__global__ __launch_bounds__(WAVES * 64, 4) void attn_kernel(
    const __bf16* __restrict__ Htg,               // [heads*FH][NN]
    const unsigned long long* __restrict__ adj_bits,
    const float* __restrict__ s1_all, const float* __restrict__ BD,
    const float* __restrict__ s2max_all, const float* __restrict__ ab_all,
    __bf16* __restrict__ accp,                    // [JSPLIT][NN][ldo]
    float* __restrict__ lg,                       // [heads*JSPLIT][NN]
    int ldo)
{
    constexpr int NJT = NN / 64 / JSPLIT;
    constexpr int NT  = FH / 16;
    const int head = blockIdx.y, js = blockIdx.z;
    const int row0 = blockIdx.x * (WAVES * 32);
    const int jt0  = js * NJT;
    const int tid = threadIdx.x;
    const int w = tid >> 6, l = tid & 63, o = l >> 4, rl = l & 15;
    const int rbase = row0 + w * 32;

    __shared__ __attribute__((aligned(16))) __bf16 hbuf[2][FH * 64];

    const float* Bv = BD + (size_t)head * 2 * NN;
    const float* Dv = Bv + NN;
    const __bf16* hg = Htg + (size_t)head * FH * NN;
    const float smax = s2max_all[head];
    const float abh = ab_all[head];

    float Au[2], Cu[2], Tb[2], lacc[2] = {0.f, 0.f};
    const unsigned long long* awp[2];
#pragma unroll
    for (int mt = 0; mt < 2; mt++) {
        int row = rbase + mt * 16 + rl;
        float z = s1_all[(size_t)head * NN + row] + abh + smax;
        float mr = fmaxf(z, 0.2f * z);
        Au[mt] = __expf(z - mr);
        Cu[mt] = __expf(0.2f * z - mr);
        Tb[mt] = __expf(fminf(-z, 80.f));
        awp[mt] = adj_bits + (size_t)row * 64;
    }
    f32x4 acc[2][NT] = {};

    stage_tile<FH, WAVES * 64>(hg + (size_t)jt0 * 64, &hbuf[0][0], tid);

#pragma unroll 2
    for (int jl = 0; jl < NJT; jl++) {
        const int b = jl & 1;
        const int jt = jt0 + jl;
        // ---- produce A-frags (P) in registers for this wave's 32 rows ----
        unsigned long long aw0 = awp[0][jt], aw1 = awp[1][jt];
        bf16x8 af[2][2];
#pragma unroll
        for (int kt = 0; kt < 2; kt++) {
            int jb = jt * 64 + kt * 32 + o * 8;
            f32x4 b0 = *(const f32x4*)(Bv + jb);
            f32x4 b1 = *(const f32x4*)(Bv + jb + 4);
            f32x4 d0 = *(const f32x4*)(Dv + jb);
            f32x4 d1 = *(const f32x4*)(Dv + jb + 4);
            unsigned int mb0 = (unsigned int)(aw0 >> ((kt * 4 + o) * 8)) & 0xFFu;
            unsigned int mb1 = (unsigned int)(aw1 >> ((kt * 4 + o) * 8)) & 0xFFu;
#pragma unroll
            for (int q = 0; q < 8; q++) {
                float bq = (q < 4) ? b0[q] : b1[q - 4];
                float dq = (q < 4) ? d0[q] : d1[q - 4];
                float p0 = (bq >= Tb[0]) ? Au[0] * bq : Cu[0] * dq;
                p0 = ((mb0 >> q) & 1u) ? p0 : 0.f;
                af[0][kt][q] = (__bf16)p0;
                lacc[0] += p0;
                float p1 = (bq >= Tb[1]) ? Au[1] * bq : Cu[1] * dq;
                p1 = ((mb1 >> q) & 1u) ? p1 : 0.f;
                af[1][kt][q] = (__bf16)p1;
                lacc[1] += p1;
            }
        }
        __syncthreads();   // drains DMA(jt); orders prev-iter hbuf reads before overwrite
        if (jl + 1 < NJT)
            stage_tile<FH, WAVES * 64>(hg + (size_t)(jt + 1) * 64, &hbuf[b ^ 1][0], tid);
        // ---- consume: B-frag once, feeds both m-tiles ----
#pragma unroll
        for (int kt = 0; kt < 2; kt++) {
#pragma unroll
            for (int nt = 0; nt < NT; nt++) {
                int f = nt * 16 + rl;
                int slot = (kt * 4 + o) ^ (rl & 7);
                bf16x8 bfr = *(const bf16x8*)(&hbuf[b][(f * 8 + slot) * 8]);
                acc[0][nt] = __builtin_amdgcn_mfma_f32_16x16x32_bf16(af[0][kt], bfr, acc[0][nt], 0, 0, 0);
                acc[1][nt] = __builtin_amdgcn_mfma_f32_16x16x32_bf16(af[1][kt], bfr, acc[1][nt], 0, 0, 0);
            }
        }
    }
    // ---- epilogue: row-sum partials + unnormalized bf16 partial acc ----
#pragma unroll
    for (int mt = 0; mt < 2; mt++) {
        lacc[mt] += __shfl_xor(lacc[mt], 16, 64);
        lacc[mt] += __shfl_xor(lacc[mt], 32, 64);
    }
    if (l < 16) {
        float* lgp = lg + ((size_t)head * JSPLIT + js) * NN + rbase;
        lgp[l] = lacc[0];
        lgp[16 + l] = lacc[1];
    }
#pragma unroll
    for (int mt = 0; mt < 2; mt++)
#pragma unroll
        for (int nt = 0; nt < NT; nt++)
#pragma unroll
            for (int r4 = 0; r4 < 4; r4++) {
                int grow = rbase + mt * 16 + o * 4 + r4;
                int gcol = head * FH + nt * 16 + rl;
                accp[((size_t)js * NN + grow) * ldo + gcol] = (__bf16)acc[mt][nt][r4];
            }
}

// ---------------- combine layer-1 partials: normalize + elu -> bf16 [N][512] ----------------
__global__ void combine1_kernel(const __bf16* __restrict__ accp, const float* __restrict__ lg,
                                __bf16* __restrict__ outb) {
    int gid = blockIdx.x * 256 + threadIdx.x;        // N * 128
    int row = gid >> 7, c4 = (gid & 127) * 4;
    int head = c4 >> 7;
    float lsum = 0.f;
#pragma unroll
    for (int js = 0; js < 8; js++) lsum += lg[((size_t)head * 8 + js) * NN + row];
    float inv = lsum > 0.f ? 1.f / lsum : 0.f;
    float v[4] = {0.f, 0.f, 0.f, 0.f};
#pragma unroll
    for (int js = 0; js < 8; js++) {
        bf16x4 t = *(const bf16x4*)(accp + ((size_t)js * NN + row) * 512 + c4);
#pragma unroll
        for (int q = 0; q < 4; q++) v[q] += (float)t[q];
    }
    bf16x4 ob;
#pragma unroll
    for (int q = 0; q < 4; q++) {
        float x = v[q] * inv;
        x = x > 0.f ? x : __expf(x) - 1.f;
        ob[q] = (__bf16)x;
    }
    *(bf16x4*)(outb + (size_t)row * 512 + c4) = ob;
}

// ---------------- combine layer-2 partials + elu + log_softmax -> out ----------------
__global__ void combine2_kernel(const __bf16* __restrict__ accp, const float* __restrict__ lg,
                                float* __restrict__ out) {
    int row = (blockIdx.x * 256 + threadIdx.x) >> 6;
    int lane = threadIdx.x & 63;
    if (row >= NN) return;
    float lsum = 0.f, v = 0.f;
#pragma unroll
    for (int js = 0; js < 16; js++) {
        lsum += lg[(size_t)js * NN + row];
        v += (float)accp[((size_t)js * NN + row) * 64 + lane];
    }
    float inv = lsum > 0.f ? 1.f / lsum : 0.f;
    v *= inv;
    v = v > 0.f ? v : __expf(v) - 1.f;
    float m = v;
#pragma unroll
    for (int off = 1; off < 64; off <<= 1) m = fmaxf(m, __shfl_xor(m, off, 64));
    float ex = __expf(v - m);
    float s = ex;
#pragma unroll
    for (int off = 1; off < 64; off <<= 1) s += __shfl_xor(s, off, 64);
    out[(size_t)row * 64 + lane] = v - m - __logf(s);
}

extern "C" void kernel_launch(void* const* d_in, const int* in_sizes, int n_in,
                              void* d_out, int out_size, void* d_ws, size_t ws_size,
                              hipStream_t stream) {
    const float* X    = (const float*)d_in[0];
    const int*   adj  = (const int*)d_in[1];
    const float* W_h  = (const float*)d_in[2];
    const float* b_h  = (const float*)d_in[3];
    const float* a1_h = (const float*)d_in[4];
    const float* a2_h = (const float*)d_in[5];
    const float* ab_h = (const float*)d_in[6];
    const float* W_o  = (const float*)d_in[7];
    const float* b_o  = (const float*)d_in[8];
    const float* a1_o = (const float*)d_in[9];
    const float* a2_o = (const float*)d_in[10];
    const float* ab_o = (const float*)d_in[11];
    float* out = (float*)d_out;

    char* ws = (char*)d_ws;
    auto alloc = [&](size_t bytes) {
        char* p = ws; ws += (bytes + 255) & ~(size_t)255; return p;
    };
    unsigned long long* adj_bits = (unsigned long long*)alloc((size_t)NN * 64 * 8); // 2 MB
    __bf16* Bt1    = (__bf16*)alloc((size_t)512 * 512 * 2);     // 512 KB
    float*  biasp  = (float*)alloc(512 * 4);
    __bf16* Bt2    = (__bf16*)alloc((size_t)64 * 512 * 2);      // 64 KB
    __bf16* Xb     = (__bf16*)alloc((size_t)NN * 512 * 2);      // 4 MB
    float*  s1h    = (float*)alloc((size_t)4 * NN * 4);         // |-- contiguous,
    float*  s2h    = (float*)alloc((size_t)4 * NN * 4);         // |   one memset
    float*  s1o    = (float*)alloc((size_t)NN * 4);             // |   (160 KB)
    float*  s2o    = (float*)alloc((size_t)NN * 4);             // |
    float*  s2maxh = (float*)alloc(4 * 4);
    float*  s2maxo = (float*)alloc(4);
    float*  BDh    = (float*)alloc((size_t)4 * 2 * NN * 4);     // 128 KB
    float*  BDo    = (float*)alloc((size_t)2 * NN * 4);         // 32 KB
    __bf16* Htg    = (__bf16*)alloc((size_t)512 * NN * 2);      // 4 MB
    __bf16* accp1  = (__bf16*)alloc((size_t)8 * NN * 512 * 2);  // 32 MB
    float*  lg1    = (float*)alloc((size_t)32 * NN * 4);        // 512 KB
    __bf16* outhb  = (__bf16*)alloc((size_t)NN * 512 * 2);      // 4 MB
    __bf16* Ht2    = (__bf16*)alloc((size_t)64 * NN * 2);       // 512 KB
    __bf16* accp2  = (__bf16*)alloc((size_t)16 * NN * 64 * 2);  // 8 MB
    float*  lg2    = (float*)alloc((size_t)16 * NN * 4);        // 256 KB  (~56 MB)

    // 0. zero the atomic s1/s2 accumulators (contiguous block)
    hipMemsetAsync(s1h, 0, (size_t)(4 + 4 + 1 + 1) * NN * 4, stream);
    // 1. adjacency -> bitmasks (single read of the 67 MB int32 matrix)
    pack_adj_kernel<<<(NN * 64) / 4, 256, 0, stream>>>(adj, adj_bits);
    // 2. prepack weights (bf16, [n][k])
    prepack_kernel<<<1024, 256, 0, stream>>>(W_h, b_h, W_o, Bt1, biasp, Bt2);
    // 3. X -> bf16
    cast_bf16_kernel<<<(NN * 512 / 4) / 256, 256, 0, stream>>>(X, Xb);
    // 4. layer-1 GEMM fused: Htg (transposed bf16) + s1h/s2h atomics
    gemm_fused_kernel<<<dim3(8, 64), 256, 0, stream>>>(
        Xb, Bt1, biasp, a1_h, a2_h, Htg, s1h, s2h, NN, 512, 512);
    // 5. s2max + Bv/Dv exp tables (layer 1, per head)
    attn_prep_kernel<<<4, 256, 0, stream>>>(s2h, s2maxh, BDh);
    // 6. attention layer 1 partials (4 heads x 8 j-splits, 128 rows/block)
    attn_kernel<128, 8, 4><<<dim3(NN / 128, 4, 8), 256, 0, stream>>>(
        Htg, adj_bits, s1h, BDh, s2maxh, ab_h, accp1, lg1, 512);
    // 7. combine -> elu -> bf16 concat features [N][512]
    combine1_kernel<<<(NN * 128) / 256, 256, 0, stream>>>(accp1, lg1, outhb);
    // 8. layer-2 GEMM fused: Ht2 (transposed bf16) + s1o/s2o atomics
    gemm_fused_kernel<<<dim3(1, 64), 256, 0, stream>>>(
        outhb, Bt2, b_o, a1_o, a2_o, Ht2, s1o, s2o, NN, 64, 512);
    // 9. s2max + Bv/Dv exp tables (layer 2)
    attn_prep_kernel<<<1, 256, 0, stream>>>(s2o, s2maxo, BDo);
    // 10. attention layer 2 partials (16 j-splits, 64 rows/block, 128 threads)
    attn_kernel<64, 16, 2><<<dim3(NN / 64, 1, 16), 128, 0, stream>>>(
        Ht2, adj_bits, s1o, BDo, s2maxo, ab_o, accp2, lg2, 64);
    // 11. combine + elu + log_softmax -> out
    combine2_kernel<<<(NN * 64) / 256, 256, 0, stream>>>(accp2, lg2, out);
}

// Round 6
// 257.708 us; speedup vs baseline: 1.3140x; 1.3140x over previous
//
#include <hip/hip_runtime.h>
#include <math.h>

#define NN 4096   // nodes

using f32x4  = __attribute__((ext_vector_type(4))) float;
using bf16x4 = __attribute__((ext_vector_type(4))) __bf16;
using bf16x8 = __attribute__((ext_vector_type(8))) __bf16;

// ---------------- async global->LDS staging (16B, XOR-swizzled chunks) ----------------
// Row f of 64 bf16 = 8 chunks of 8; LDS slot s of row f holds global chunk s^(f&7).
template<int FH, int NTH>
__device__ __forceinline__ void stage_tile(const __bf16* __restrict__ hgp,
                                           __bf16* dst, int tid) {
#pragma unroll
    for (int it = 0; it < FH * 8 / NTH; it++) {
        int c = tid + it * NTH;
        int f = c >> 3, sl = c & 7;
        int g = sl ^ (f & 7);
        __builtin_amdgcn_global_load_lds(
            (const __attribute__((address_space(1))) void*)(hgp + (size_t)f * NN + g * 8),
            (__attribute__((address_space(3))) void*)(dst + (size_t)c * 8), 16, 0, 0);
    }
}

__device__ __forceinline__ void stage_g(const __bf16* __restrict__ base, int ldk,
                                        __bf16* dst, int tid) {
#pragma unroll
    for (int it = 0; it < 2; it++) {
        int c = tid + it * 256;
        int f = c >> 3, sl = c & 7;
        int g = sl ^ (f & 7);
        __builtin_amdgcn_global_load_lds(
            (const __attribute__((address_space(1))) void*)(base + (size_t)f * ldk + g * 8),
            (__attribute__((address_space(3))) void*)(dst + (size_t)c * 8), 16, 0, 0);
    }
}

// ---------------- adjacency -> bitmask ----------------
__global__ void pack_adj_kernel(const int* __restrict__ adj,
                                unsigned long long* __restrict__ bits) {
    int gw = (blockIdx.x * blockDim.x + threadIdx.x) >> 6;
    int lane = threadIdx.x & 63;
    int v = adj[(size_t)gw * 64 + lane];
    unsigned long long m = __ballot(v > 0);
    if (lane == 0) bits[gw] = m;
}

// ---------------- prepack: W_h -> Bt1[n=512][k=512] bf16, W_o -> Bt2[n=64][k=512] ----
__global__ void prepack_kernel(const float* __restrict__ W_h, const float* __restrict__ b_h,
                               const float* __restrict__ W_o,
                               __bf16* __restrict__ Bt1, float* __restrict__ biasp,
                               __bf16* __restrict__ Bt2) {
    int idx = blockIdx.x * 256 + threadIdx.x;   // 512*512
    {
        int n = idx >> 9, k = idx & 511;
        int h = n >> 7, f = n & 127;
        Bt1[idx] = (__bf16)W_h[(size_t)h * 512 * 128 + k * 128 + f];
    }
    if (idx < 64 * 512) {
        int n = idx >> 9, k = idx & 511;
        Bt2[idx] = (__bf16)W_o[k * 64 + n];
    }
    if (idx < 512) biasp[idx] = b_h[idx];
}

// ---------------- fp32 -> bf16 cast ----------------
__global__ void cast_bf16_kernel(const float* __restrict__ src, __bf16* __restrict__ dst) {
    int i = blockIdx.x * 256 + threadIdx.x;
    f32x4 v = *(const f32x4*)(src + (size_t)i * 4);
    bf16x4 o;
#pragma unroll
    for (int q = 0; q < 4; q++) o[q] = (__bf16)v[q];
    *(bf16x4*)(dst + (size_t)i * 4) = o;
}

// ---------------- fused bf16 MFMA GEMM ----------------
// Ht[col][row] = bf16( (A @ Bt^T)[row][col] + bias[col] )   (transposed store)
// s1[head][row] += sum_col h*a1[col], s2 likewise (fp32 atomics; head = bn>>7)
__global__ __launch_bounds__(256) void gemm_fused_kernel(
    const __bf16* __restrict__ A, const __bf16* __restrict__ Bt,
    const float* __restrict__ bias,
    const float* __restrict__ a1, const float* __restrict__ a2,
    __bf16* __restrict__ Ht, float* __restrict__ s1, float* __restrict__ s2,
    int M, int N, int K)
{
    __shared__ __attribute__((aligned(16))) __bf16 As[2][64 * 64];
    __shared__ __attribute__((aligned(16))) __bf16 Bs[2][64 * 64];
    const int tid = threadIdx.x, w = tid >> 6, l = tid & 63, o = l >> 4, rl = l & 15;
    const int bm = blockIdx.y * 64, bn = blockIdx.x * 64;
    f32x4 acc[4] = {};
    stage_g(A + (size_t)bm * K, K, &As[0][0], tid);
    stage_g(Bt + (size_t)bn * K, K, &Bs[0][0], tid);
    const int KB = K / 64;
    for (int kb = 0; kb < KB; kb++) {
        int b = kb & 1;
        __syncthreads();
        if (kb + 1 < KB) {
            stage_g(A + (size_t)bm * K + (kb + 1) * 64, K, &As[b ^ 1][0], tid);
            stage_g(Bt + (size_t)bn * K + (kb + 1) * 64, K, &Bs[b ^ 1][0], tid);
        }
#pragma unroll
        for (int kt = 0; kt < 2; kt++) {
            int ra = w * 16 + rl;
            int cg = kt * 4 + o;
            bf16x8 af = *(const bf16x8*)(&As[b][(ra * 8 + (cg ^ (ra & 7))) * 8]);
#pragma unroll
            for (int nt = 0; nt < 4; nt++) {
                int rb = nt * 16 + rl;
                bf16x8 bfr = *(const bf16x8*)(&Bs[b][(rb * 8 + (cg ^ (rb & 7))) * 8]);
                acc[nt] = __builtin_amdgcn_mfma_f32_16x16x32_bf16(af, bfr, acc[nt], 0, 0, 0);
            }
        }
    }
    const int head = bn >> 7;
    const int row_base = bm + w * 16 + o * 4;
    float p1[4] = {0.f, 0.f, 0.f, 0.f}, p2[4] = {0.f, 0.f, 0.f, 0.f};
#pragma unroll
    for (int nt = 0; nt < 4; nt++) {
        int col = bn + nt * 16 + rl;
        float bv = bias[col];
        float a1v = a1[col], a2v = a2[col];
        bf16x4 hv;
#pragma unroll
        for (int r4 = 0; r4 < 4; r4++) {
            float h = acc[nt][r4] + bv;
            hv[r4] = (__bf16)h;
            p1[r4] += h * a1v;
            p2[r4] += h * a2v;
        }
        *(bf16x4*)(Ht + (size_t)col * M + row_base) = hv;
    }
#pragma unroll
    for (int r4 = 0; r4 < 4; r4++)
#pragma unroll
        for (int off = 1; off < 16; off <<= 1) {
            p1[r4] += __shfl_xor(p1[r4], off, 64);
            p2[r4] += __shfl_xor(p2[r4], off, 64);
        }
    if (rl == 0)
#pragma unroll
        for (int r4 = 0; r4 < 4; r4++) {
            atomicAdd(&s1[(size_t)head * M + row_base + r4], p1[r4]);
            atomicAdd(&s2[(size_t)head * M + row_base + r4], p2[r4]);
        }
}

// ---------------- attn prep: s2max + Bv/Dv exp tables per head ----------------
// Bv[j]=exp(s2_j - s2max) <= 1,  Dv[j]=exp(0.2(s2_j - s2max)) <= 1.
__global__ void attn_prep_kernel(const float* __restrict__ s2_all,
                                 float* __restrict__ s2max_all,
                                 float* __restrict__ BD) {
    const int head = blockIdx.x;
    const float* s2 = s2_all + (size_t)head * NN;
    const int t = threadIdx.x;
    float m = -INFINITY;
    for (int i = t; i < NN; i += 256) m = fmaxf(m, s2[i]);
#pragma unroll
    for (int off = 1; off < 64; off <<= 1) m = fmaxf(m, __shfl_xor(m, off, 64));
    __shared__ float red[4];
    if ((t & 63) == 0) red[t >> 6] = m;
    __syncthreads();
    float smax = fmaxf(fmaxf(red[0], red[1]), fmaxf(red[2], red[3]));
    if (t == 0) s2max_all[head] = smax;
    float* Bv = BD + (size_t)head * 2 * NN;
    float* Dv = Bv + NN;
    for (int i = t; i < NN; i += 256) {
        float d = s2[i] - smax;
        Bv[i] = __expf(d);
        Dv[i] = __expf(0.2f * d);
    }
}

// ---------------- MFMA attention: in-register A-frags, separable exp ----------------
// p_ij = mask * ( s1_i+s2_j>=0 ? A_i*Bv_j : C_i*Dv_j ),  all factors <= 1.
// Wave owns 32 rows (2 m-tiles), loops ALL n-tiles; ONE barrier per j-tile.
// Partial acc is stored in C-FRAGMENT-NATIVE layout:
//   accp[js][head][g][mt][nt][lane][reg]  (g = 32-row group = blockIdx.x*WAVES+w)
// so each store is bf16x4 at lane*8B -> 512 B contiguous per instruction
// (R5's row-major C-layout scatter caused ~13x HBM write amplification).
template<int FH, int JSPLIT, int WAVES>
__global__ __launch_bounds__(WAVES * 64, 4) void attn_kernel(
    const __bf16* __restrict__ Htg,               // [heads*FH][NN]
    const unsigned long long* __restrict__ adj_bits,
    const float* __restrict__ s1_all, const float* __restrict__ BD,
    const float* __restrict__ s2max_all, const float* __restrict__ ab_all,
    __bf16* __restrict__ accp,                    // C-native partials
    float* __restrict__ lg)                       // [heads][JSPLIT][NN]
{
    constexpr int NJT = NN / 64 / JSPLIT;
    constexpr int NT  = FH / 16;
    const int head = blockIdx.y, js = blockIdx.z;
    const int row0 = blockIdx.x * (WAVES * 32);
    const int jt0  = js * NJT;
    const int tid = threadIdx.x;
    const int w = tid >> 6, l = tid & 63, o = l >> 4;
    const int rbase = row0 + w * 32;

    __shared__ __attribute__((aligned(16))) __bf16 hbuf[2][FH * 64];

    const float* Bv = BD + (size_t)head * 2 * NN;
    const float* Dv = Bv + NN;
    const __bf16* hg = Htg + (size_t)head * FH * NN;
    const float smax = s2max_all[head];
    const float abh = ab_all[head];

    float Au[2], Cu[2], Tb[2], lacc[2] = {0.f, 0.f};
    const unsigned long long* awp[2];
#pragma unroll
    for (int mt = 0; mt < 2; mt++) {
        int row = rbase + mt * 16 + (l & 15);
        float z = s1_all[(size_t)head * NN + row] + abh + smax;
        float mr = fmaxf(z, 0.2f * z);
        Au[mt] = __expf(z - mr);
        Cu[mt] = __expf(0.2f * z - mr);
        Tb[mt] = __expf(fminf(-z, 80.f));
        awp[mt] = adj_bits + (size_t)row * 64;
    }
    f32x4 acc[2][NT] = {};

    stage_tile<FH, WAVES * 64>(hg + (size_t)jt0 * 64, &hbuf[0][0], tid);

    for (int jl = 0; jl < NJT; jl++) {
        const int b = jl & 1;
        const int jt = jt0 + jl;
        // ---- produce A-frags (P) in registers for this wave's 32 rows ----
        unsigned long long aw0 = awp[0][jt], aw1 = awp[1][jt];
        bf16x8 af[2][2];
#pragma unroll
        for (int kt = 0; kt < 2; kt++) {
            int jb = jt * 64 + kt * 32 + o * 8;
            f32x4 b0 = *(const f32x4*)(Bv + jb);
            f32x4 b1 = *(const f32x4*)(Bv + jb + 4);
            f32x4 d0 = *(const f32x4*)(Dv + jb);
            f32x4 d1 = *(const f32x4*)(Dv + jb + 4);
            unsigned int mb0 = (unsigned int)(aw0 >> ((kt * 4 + o) * 8)) & 0xFFu;
            unsigned int mb1 = (unsigned int)(aw1 >> ((kt * 4 + o) * 8)) & 0xFFu;
#pragma unroll
            for (int q = 0; q < 8; q++) {
                float bq = (q < 4) ? b0[q] : b1[q - 4];
                float dq = (q < 4) ? d0[q] : d1[q - 4];
                float p0 = (bq >= Tb[0]) ? Au[0] * bq : Cu[0] * dq;
                p0 = ((mb0 >> q) & 1u) ? p0 : 0.f;
                af[0][kt][q] = (__bf16)p0;
                lacc[0] += p0;
                float p1 = (bq >= Tb[1]) ? Au[1] * bq : Cu[1] * dq;
                p1 = ((mb1 >> q) & 1u) ? p1 : 0.f;
                af[1][kt][q] = (__bf16)p1;
                lacc[1] += p1;
            }
        }
        __syncthreads();   // drains DMA(jt); orders prev-iter hbuf reads before overwrite
        if (jl + 1 < NJT)
            stage_tile<FH, WAVES * 64>(hg + (size_t)(jt + 1) * 64, &hbuf[b ^ 1][0], tid);
        // ---- consume: B-frag once, feeds both m-tiles ----
#pragma unroll
        for (int kt = 0; kt < 2; kt++) {
#pragma unroll
            for (int nt = 0; nt < NT; nt++) {
                int f = nt * 16 + (l & 15);
                int slot = (kt * 4 + o) ^ (f & 7);
                bf16x8 bfr = *(const bf16x8*)(&hbuf[b][(f * 8 + slot) * 8]);
                acc[0][nt] = __builtin_amdgcn_mfma_f32_16x16x32_bf16(af[0][kt], bfr, acc[0][nt], 0, 0, 0);
                acc[1][nt] = __builtin_amdgcn_mfma_f32_16x16x32_bf16(af[1][kt], bfr, acc[1][nt], 0, 0, 0);
            }
        }
    }
    // ---- epilogue: row-sum partials + C-native coalesced partial store ----
#pragma unroll
    for (int mt = 0; mt < 2; mt++) {
        lacc[mt] += __shfl_xor(lacc[mt], 16, 64);
        lacc[mt] += __shfl_xor(lacc[mt], 32, 64);
    }
    if (l < 16) {
        float* lgp = lg + ((size_t)head * JSPLIT + js) * NN + rbase;
        lgp[l] = lacc[0];
        lgp[16 + l] = lacc[1];
    }
    const int g = blockIdx.x * WAVES + w;
    size_t wbase = ((((size_t)js * gridDim.y + head) * (gridDim.x * WAVES) + g) * 2)
                   * (size_t)(NT * 256);
#pragma unroll
    for (int mt = 0; mt < 2; mt++)
#pragma unroll
        for (int nt = 0; nt < NT; nt++) {
            bf16x4 t;
#pragma unroll
            for (int r4 = 0; r4 < 4; r4++) t[r4] = (__bf16)acc[mt][nt][r4];
            *(bf16x4*)(accp + wbase + (size_t)(mt * NT + nt) * 256 + l * 4) = t;
        }
}

// ---------------- reduce j-split row sums -> reciprocal per (head,row) ----------------
__global__ void lsum_kernel(const float* __restrict__ lg, float* __restrict__ inv, int S) {
    int i = blockIdx.x * 256 + threadIdx.x;        // i = head*NN + row
    int head = i >> 12, row = i & (NN - 1);
    float s = 0.f;
    for (int j = 0; j < S; j++) s += lg[((size_t)head * S + j) * NN + row];
    inv[i] = s > 0.f ? 1.f / s : 0.f;
}

// ---------------- combine layer-1: sum js, normalize, elu -> bf16 [N][512] ----------------
// accp layout: [js][head(4)][g(128)][mt(2)][nt(8)][lane(64)][reg(4)]
__global__ void combine1_kernel(const __bf16* __restrict__ accp,
                                const float* __restrict__ inv1,
                                __bf16* __restrict__ outb) {
    int gid = blockIdx.x * 256 + threadIdx.x;      // per head: 128*2*8*64 = 131072
    int l = gid & 63, nt = (gid >> 6) & 7, mt = (gid >> 9) & 1, g = gid >> 10;
    int head = blockIdx.y;
    int o = l >> 4, rl = l & 15;
    const size_t stride_js = (size_t)4 * 128 * 2 * 8 * 256;
    size_t base = ((((size_t)head * 128 + g) * 2 + mt) * 8 + nt) * 256 + l * 4;
    float v[4] = {0.f, 0.f, 0.f, 0.f};
#pragma unroll
    for (int js = 0; js < 8; js++) {
        bf16x4 t = *(const bf16x4*)(accp + base + js * stride_js);
#pragma unroll
        for (int q = 0; q < 4; q++) v[q] += (float)t[q];
    }
    int row0 = g * 32 + mt * 16 + o * 4;
    int col = head * 128 + nt * 16 + rl;
#pragma unroll
    for (int q = 0; q < 4; q++) {
        float x = v[q] * inv1[head * NN + row0 + q];
        x = x > 0.f ? x : __expf(x) - 1.f;
        outb[(size_t)(row0 + q) * 512 + col] = (__bf16)x;
    }
}

// ---------------- combine layer-2 + elu + log_softmax -> out ----------------
// accp layout: [js][g(128)][mt(2)][nt(4)][lane(64)][reg(4)]; wave per row.
__global__ void combine2_kernel(const __bf16* __restrict__ accp,
                                const float* __restrict__ inv2,
                                float* __restrict__ out) {
    int row = blockIdx.x * 4 + (threadIdx.x >> 6);
    int lam = threadIdx.x & 63;
    int g = row >> 5, mt = (row >> 4) & 1, o = (row >> 2) & 3, r4 = row & 3;
    int nt = lam >> 4, rl = lam & 15;
    int l = o * 16 + rl;
    const size_t stride_js = (size_t)128 * 2 * 4 * 256;
    size_t base = (((size_t)g * 2 + mt) * 4 + nt) * 256 + (size_t)l * 4 + r4;
    float v = 0.f;
#pragma unroll
    for (int js = 0; js < 16; js++) v += (float)accp[base + js * stride_js];
    v *= inv2[row];
    v = v > 0.f ? v : __expf(v) - 1.f;
    float m = v;
#pragma unroll
    for (int off = 1; off < 64; off <<= 1) m = fmaxf(m, __shfl_xor(m, off, 64));
    float ex = __expf(v - m);
    float s = ex;
#pragma unroll
    for (int off = 1; off < 64; off <<= 1) s += __shfl_xor(s, off, 64);
    out[(size_t)row * 64 + lam] = v - m - __logf(s);
}

extern "C" void kernel_launch(void* const* d_in, const int* in_sizes, int n_in,
                              void* d_out, int out_size, void* d_ws, size_t ws_size,
                              hipStream_t stream) {
    const float* X    = (const float*)d_in[0];
    const int*   adj  = (const int*)d_in[1];
    const float* W_h  = (const float*)d_in[2];
    const float* b_h  = (const float*)d_in[3];
    const float* a1_h = (const float*)d_in[4];
    const float* a2_h = (const float*)d_in[5];
    const float* ab_h = (const float*)d_in[6];
    const float* W_o  = (const float*)d_in[7];
    const float* b_o  = (const float*)d_in[8];
    const float* a1_o = (const float*)d_in[9];
    const float* a2_o = (const float*)d_in[10];
    const float* ab_o = (const float*)d_in[11];
    float* out = (float*)d_out;

    char* ws = (char*)d_ws;
    auto alloc = [&](size_t bytes) {
        char* p = ws; ws += (bytes + 255) & ~(size_t)255; return p;
    };
    unsigned long long* adj_bits = (unsigned long long*)alloc((size_t)NN * 64 * 8); // 2 MB
    __bf16* Bt1    = (__bf16*)alloc((size_t)512 * 512 * 2);     // 512 KB
    float*  biasp  = (float*)alloc(512 * 4);
    __bf16* Bt2    = (__bf16*)alloc((size_t)64 * 512 * 2);      // 64 KB
    __bf16* Xb     = (__bf16*)alloc((size_t)NN * 512 * 2);      // 4 MB
    float*  s1h    = (float*)alloc((size_t)4 * NN * 4);         // |-- contiguous,
    float*  s2h    = (float*)alloc((size_t)4 * NN * 4);         // |   one memset
    float*  s1o    = (float*)alloc((size_t)NN * 4);             // |   (160 KB)
    float*  s2o    = (float*)alloc((size_t)NN * 4);             // |
    float*  s2maxh = (float*)alloc(4 * 4);
    float*  s2maxo = (float*)alloc(4);
    float*  BDh    = (float*)alloc((size_t)4 * 2 * NN * 4);     // 128 KB
    float*  BDo    = (float*)alloc((size_t)2 * NN * 4);         // 32 KB
    __bf16* Htg    = (__bf16*)alloc((size_t)512 * NN * 2);      // 4 MB
    __bf16* accp1  = (__bf16*)alloc((size_t)8 * 4 * 128 * 2 * 8 * 256 * 2);  // 32 MB
    float*  lg1    = (float*)alloc((size_t)32 * NN * 4);        // 512 KB
    float*  inv1   = (float*)alloc((size_t)4 * NN * 4);         // 64 KB
    __bf16* outhb  = (__bf16*)alloc((size_t)NN * 512 * 2);      // 4 MB
    __bf16* Ht2    = (__bf16*)alloc((size_t)64 * NN * 2);       // 512 KB
    __bf16* accp2  = (__bf16*)alloc((size_t)16 * 128 * 2 * 4 * 256 * 2);     // 8 MB
    float*  lg2    = (float*)alloc((size_t)16 * NN * 4);        // 256 KB
    float*  inv2   = (float*)alloc((size_t)NN * 4);             // 16 KB  (~56 MB)

    // 0. zero the atomic s1/s2 accumulators (contiguous block)
    hipMemsetAsync(s1h, 0, (size_t)(4 + 4 + 1 + 1) * NN * 4, stream);
    // 1. adjacency -> bitmasks (single read of the 67 MB int32 matrix)
    pack_adj_kernel<<<(NN * 64) / 4, 256, 0, stream>>>(adj, adj_bits);
    // 2. prepack weights (bf16, [n][k])
    prepack_kernel<<<1024, 256, 0, stream>>>(W_h, b_h, W_o, Bt1, biasp, Bt2);
    // 3. X -> bf16
    cast_bf16_kernel<<<(NN * 512 / 4) / 256, 256, 0, stream>>>(X, Xb);
    // 4. layer-1 GEMM fused: Htg (transposed bf16) + s1h/s2h atomics
    gemm_fused_kernel<<<dim3(8, 64), 256, 0, stream>>>(
        Xb, Bt1, biasp, a1_h, a2_h, Htg, s1h, s2h, NN, 512, 512);
    // 5. s2max + Bv/Dv exp tables (layer 1, per head)
    attn_prep_kernel<<<4, 256, 0, stream>>>(s2h, s2maxh, BDh);
    // 6. attention layer 1 partials (4 heads x 8 j-splits, 128 rows/block)
    attn_kernel<128, 8, 4><<<dim3(NN / 128, 4, 8), 256, 0, stream>>>(
        Htg, adj_bits, s1h, BDh, s2maxh, ab_h, accp1, lg1);
    // 7. per-row reciprocal sums (layer 1)
    lsum_kernel<<<(4 * NN) / 256, 256, 0, stream>>>(lg1, inv1, 8);
    // 8. combine -> elu -> bf16 concat features [N][512]
    combine1_kernel<<<dim3(512, 4), 256, 0, stream>>>(accp1, inv1, outhb);
    // 9. layer-2 GEMM fused: Ht2 (transposed bf16) + s1o/s2o atomics
    gemm_fused_kernel<<<dim3(1, 64), 256, 0, stream>>>(
        outhb, Bt2, b_o, a1_o, a2_o, Ht2, s1o, s2o, NN, 64, 512);
    // 10. s2max + Bv/Dv exp tables (layer 2)
    attn_prep_kernel<<<1, 256, 0, stream>>>(s2o, s2maxo, BDo);
    // 11. attention layer 2 partials (16 j-splits, 64 rows/block, 128 threads)
    attn_kernel<64, 16, 2><<<dim3(NN / 64, 1, 16), 128, 0, stream>>>(
        Ht2, adj_bits, s1o, BDo, s2maxo, ab_o, accp2, lg2);
    // 12. per-row reciprocal sums (layer 2)
    lsum_kernel<<<NN / 256, 256, 0, stream>>>(lg2, inv2, 16);
    // 13. combine + elu + log_softmax -> out
    combine2_kernel<<<NN / 4, 256, 0, stream>>>(accp2, inv2, out);
}

// Round 8
// 252.029 us; speedup vs baseline: 1.3436x; 1.0225x over previous
//
#include <hip/hip_runtime.h>
#include <math.h>

#define NN 4096   // nodes

using f32x2  = __attribute__((ext_vector_type(2))) float;
using f32x4  = __attribute__((ext_vector_type(4))) float;
using bf16x4 = __attribute__((ext_vector_type(4))) __bf16;
using bf16x8 = __attribute__((ext_vector_type(8))) __bf16;

// ---------------- async global->LDS staging (16B, XOR-swizzled chunks) ----------------
// Row f of 64 bf16 = 8 chunks of 8; LDS slot s of row f holds global chunk s^(f&7).
template<int FH, int NTH>
__device__ __forceinline__ void stage_tile(const __bf16* __restrict__ hgp,
                                           __bf16* dst, int tid) {
#pragma unroll
    for (int it = 0; it < FH * 8 / NTH; it++) {
        int c = tid + it * NTH;
        int f = c >> 3, sl = c & 7;
        int g = sl ^ (f & 7);
        __builtin_amdgcn_global_load_lds(
            (const __attribute__((address_space(1))) void*)(hgp + (size_t)f * NN + g * 8),
            (__attribute__((address_space(3))) void*)(dst + (size_t)c * 8), 16, 0, 0);
    }
}

__device__ __forceinline__ void stage_g(const __bf16* __restrict__ base, int ldk,
                                        __bf16* dst, int tid) {
#pragma unroll
    for (int it = 0; it < 2; it++) {
        int c = tid + it * 256;
        int f = c >> 3, sl = c & 7;
        int g = sl ^ (f & 7);
        __builtin_amdgcn_global_load_lds(
            (const __attribute__((address_space(1))) void*)(base + (size_t)f * ldk + g * 8),
            (__attribute__((address_space(3))) void*)(dst + (size_t)c * 8), 16, 0, 0);
    }
}

// ---------------- adjacency -> bitmask ----------------
__global__ void pack_adj_kernel(const int* __restrict__ adj,
                                unsigned long long* __restrict__ bits) {
    int gw = (blockIdx.x * blockDim.x + threadIdx.x) >> 6;
    int lane = threadIdx.x & 63;
    int v = adj[(size_t)gw * 64 + lane];
    unsigned long long m = __ballot(v > 0);
    if (lane == 0) bits[gw] = m;
}

// ---------------- prepack: W_h -> Bt1[n=512][k=512] bf16, W_o -> Bt2[n=64][k=512] ----
__global__ void prepack_kernel(const float* __restrict__ W_h, const float* __restrict__ b_h,
                               const float* __restrict__ W_o,
                               __bf16* __restrict__ Bt1, float* __restrict__ biasp,
                               __bf16* __restrict__ Bt2) {
    int idx = blockIdx.x * 256 + threadIdx.x;   // 512*512
    {
        int n = idx >> 9, k = idx & 511;
        int h = n >> 7, f = n & 127;
        Bt1[idx] = (__bf16)W_h[(size_t)h * 512 * 128 + k * 128 + f];
    }
    if (idx < 64 * 512) {
        int n = idx >> 9, k = idx & 511;
        Bt2[idx] = (__bf16)W_o[k * 64 + n];
    }
    if (idx < 512) biasp[idx] = b_h[idx];
}

// ---------------- fp32 -> bf16 cast ----------------
__global__ void cast_bf16_kernel(const float* __restrict__ src, __bf16* __restrict__ dst) {
    int i = blockIdx.x * 256 + threadIdx.x;
    f32x4 v = *(const f32x4*)(src + (size_t)i * 4);
    bf16x4 o;
#pragma unroll
    for (int q = 0; q < 4; q++) o[q] = (__bf16)v[q];
    *(bf16x4*)(dst + (size_t)i * 4) = o;
}

// ---------------- fused bf16 MFMA GEMM (layer 1) ----------------
// Ht[col][row] = bf16( (A @ Bt^T)[row][col] + bias[col] )   (transposed store)
// s1[head][row] += sum_col h*a1[col], s2 likewise (fp32 atomics; head = bn>>7)
__global__ __launch_bounds__(256) void gemm_fused_kernel(
    const __bf16* __restrict__ A, const __bf16* __restrict__ Bt,
    const float* __restrict__ bias,
    const float* __restrict__ a1, const float* __restrict__ a2,
    __bf16* __restrict__ Ht, float* __restrict__ s1, float* __restrict__ s2,
    int M, int N, int K)
{
    __shared__ __attribute__((aligned(16))) __bf16 As[2][64 * 64];
    __shared__ __attribute__((aligned(16))) __bf16 Bs[2][64 * 64];
    const int tid = threadIdx.x, w = tid >> 6, l = tid & 63, o = l >> 4, rl = l & 15;
    const int bm = blockIdx.y * 64, bn = blockIdx.x * 64;
    f32x4 acc[4] = {};
    stage_g(A + (size_t)bm * K, K, &As[0][0], tid);
    stage_g(Bt + (size_t)bn * K, K, &Bs[0][0], tid);
    const int KB = K / 64;
    for (int kb = 0; kb < KB; kb++) {
        int b = kb & 1;
        __syncthreads();
        if (kb + 1 < KB) {
            stage_g(A + (size_t)bm * K + (kb + 1) * 64, K, &As[b ^ 1][0], tid);
            stage_g(Bt + (size_t)bn * K + (kb + 1) * 64, K, &Bs[b ^ 1][0], tid);
        }
#pragma unroll
        for (int kt = 0; kt < 2; kt++) {
            int ra = w * 16 + rl;
            int cg = kt * 4 + o;
            bf16x8 af = *(const bf16x8*)(&As[b][(ra * 8 + (cg ^ (ra & 7))) * 8]);
#pragma unroll
            for (int nt = 0; nt < 4; nt++) {
                int rb = nt * 16 + rl;
                bf16x8 bfr = *(const bf16x8*)(&Bs[b][(rb * 8 + (cg ^ (rb & 7))) * 8]);
                acc[nt] = __builtin_amdgcn_mfma_f32_16x16x32_bf16(af, bfr, acc[nt], 0, 0, 0);
            }
        }
    }
    const int head = bn >> 7;
    const int row_base = bm + w * 16 + o * 4;
    float p1[4] = {0.f, 0.f, 0.f, 0.f}, p2[4] = {0.f, 0.f, 0.f, 0.f};
#pragma unroll
    for (int nt = 0; nt < 4; nt++) {
        int col = bn + nt * 16 + rl;
        float bv = bias[col];
        float a1v = a1[col], a2v = a2[col];
        bf16x4 hv;
#pragma unroll
        for (int r4 = 0; r4 < 4; r4++) {
            float h = acc[nt][r4] + bv;
            hv[r4] = (__bf16)h;
            p1[r4] += h * a1v;
            p2[r4] += h * a2v;
        }
        *(bf16x4*)(Ht + (size_t)col * M + row_base) = hv;
    }
#pragma unroll
    for (int r4 = 0; r4 < 4; r4++)
#pragma unroll
        for (int off = 1; off < 16; off <<= 1) {
            p1[r4] += __shfl_xor(p1[r4], off, 64);
            p2[r4] += __shfl_xor(p2[r4], off, 64);
        }
    if (rl == 0)
#pragma unroll
        for (int r4 = 0; r4 < 4; r4++) {
            atomicAdd(&s1[(size_t)head * M + row_base + r4], p1[r4]);
            atomicAdd(&s2[(size_t)head * M + row_base + r4], p2[r4]);
        }
}

// ---------------- layer-2 GEMM, split-K x4 into fp32 partials ----------------
// Cp[ks][M][64] = outhb[:, ks*128:(ks+1)*128] @ Bt2[:, same]^T   (no bias)
__global__ __launch_bounds__(256) void gemm_slice_kernel(
    const __bf16* __restrict__ A, const __bf16* __restrict__ Bt,
    float* __restrict__ Cp, int M, int K)
{
    __shared__ __attribute__((aligned(16))) __bf16 As[2][64 * 64];
    __shared__ __attribute__((aligned(16))) __bf16 Bs[2][64 * 64];
    const int tid = threadIdx.x, w = tid >> 6, l = tid & 63, o = l >> 4, rl = l & 15;
    const int ks = blockIdx.x, bm = blockIdx.y * 64;
    const int kb0 = ks * 2;
    f32x4 acc[4] = {};
    stage_g(A + (size_t)bm * K + kb0 * 64, K, &As[0][0], tid);
    stage_g(Bt + kb0 * 64, K, &Bs[0][0], tid);
    for (int kb = 0; kb < 2; kb++) {
        __syncthreads();
        if (kb == 0) {
            stage_g(A + (size_t)bm * K + (kb0 + 1) * 64, K, &As[1][0], tid);
            stage_g(Bt + (kb0 + 1) * 64, K, &Bs[1][0], tid);
        }
#pragma unroll
        for (int kt = 0; kt < 2; kt++) {
            int ra = w * 16 + rl;
            int cg = kt * 4 + o;
            bf16x8 af = *(const bf16x8*)(&As[kb][(ra * 8 + (cg ^ (ra & 7))) * 8]);
#pragma unroll
            for (int nt = 0; nt < 4; nt++) {
                int rb = nt * 16 + rl;
                bf16x8 bfr = *(const bf16x8*)(&Bs[kb][(rb * 8 + (cg ^ (rb & 7))) * 8]);
                acc[nt] = __builtin_amdgcn_mfma_f32_16x16x32_bf16(af, bfr, acc[nt], 0, 0, 0);
            }
        }
    }
    float* cp = Cp + (size_t)ks * M * 64;
#pragma unroll
    for (int nt = 0; nt < 4; nt++)
#pragma unroll
        for (int r4 = 0; r4 < 4; r4++) {
            int row = bm + w * 16 + o * 4 + r4;
            int col = nt * 16 + rl;
            cp[(size_t)row * 64 + col] = acc[nt][r4];
        }
}

// ---------------- sum slices + bias -> Ht2 (transposed bf16) + s1o/s2o dots ----------
__global__ __launch_bounds__(256) void s12t_kernel(
    const float* __restrict__ h2p, const float* __restrict__ b_o,
    const float* __restrict__ a1, const float* __restrict__ a2,
    __bf16* __restrict__ Ht2, float* __restrict__ s1, float* __restrict__ s2)
{
    __shared__ float tile[64][72];
    const int row0 = blockIdx.x * 64;
    const int tid = threadIdx.x;
#pragma unroll
    for (int v = 0; v < 4; v++) {
        int i4 = tid + v * 256;                 // f32x4 index (1024 total)
        int r = i4 >> 4, c0 = (i4 & 15) * 4;
        f32x4 s = *(const f32x4*)(b_o + c0);
#pragma unroll
        for (int ks = 0; ks < 4; ks++)
            s += *(const f32x4*)(h2p + ((size_t)ks * NN + row0 + r) * 64 + c0);
        *(f32x4*)(&tile[r][c0]) = s;
    }
    __syncthreads();
    const int rq = tid >> 6, l = tid & 63;
    const float a1v = a1[l], a2v = a2[l];
    bf16x8 hvlo = {}, hvhi = {};
#pragma unroll
    for (int r = 0; r < 16; r++) {
        int row = rq * 16 + r;
        float h = tile[row][l];
        if (r < 8) hvlo[r] = (__bf16)h; else hvhi[r - 8] = (__bf16)h;
        float v1 = h * a1v, v2 = h * a2v;
#pragma unroll
        for (int off = 1; off < 64; off <<= 1) {
            v1 += __shfl_xor(v1, off, 64);
            v2 += __shfl_xor(v2, off, 64);
        }
        if (l == 0) { s1[row0 + row] = v1; s2[row0 + row] = v2; }
    }
    *(bf16x8*)(Ht2 + (size_t)l * NN + row0 + rq * 16) = hvlo;
    *(bf16x8*)(Ht2 + (size_t)l * NN + row0 + rq * 16 + 8) = hvhi;
}

// ---------------- attn prep: s2max + Bv/Dv exp tables per head ----------------
__global__ void attn_prep_kernel(const float* __restrict__ s2_all,
                                 float* __restrict__ s2max_all,
                                 float* __restrict__ BD) {
    const int head = blockIdx.x;
    const float* s2 = s2_all + (size_t)head * NN;
    const int t = threadIdx.x;
    float m = -INFINITY;
    for (int i = t; i < NN; i += 256) m = fmaxf(m, s2[i]);
#pragma unroll
    for (int off = 1; off < 64; off <<= 1) m = fmaxf(m, __shfl_xor(m, off, 64));
    __shared__ float red[4];
    if ((t & 63) == 0) red[t >> 6] = m;
    __syncthreads();
    float smax = fmaxf(fmaxf(red[0], red[1]), fmaxf(red[2], red[3]));
    if (t == 0) s2max_all[head] = smax;
    float* Bv = BD + (size_t)head * 2 * NN;
    float* Dv = Bv + NN;
    for (int i = t; i < NN; i += 256) {
        float d = s2[i] - smax;
        Bv[i] = __expf(d);
        Dv[i] = __expf(0.2f * d);
    }
}

// ---------------- MFMA attention: in-register A-frags, separable exp ----------------
// exp(lrelu(x)-m) = max(A_i*Bv_j, C_i*Dv_j) EXACTLY (exp monotone); mask applied
// via sign-extended bit AND; f32x2 packed mul/max/add. Wave owns 32 rows, loops
// ALL n-tiles; ONE barrier per j-tile. Adjacency words: 2-register software
// pipeline (next-iter prefetch), NOT an array (dynamic-indexed array -> scratch).
// XCD swizzle: all row-blocks of one (head,js) group share bid%8 -> same XCD L2.
// C-fragment-native partial store (512 B contiguous per instruction).
// Global-bound m => j-split partials add exactly; combine kernels finish.
template<int FH, int JSPLIT, int WAVES, int HEADS>
__global__ __launch_bounds__(WAVES * 64, 4) void attn_kernel(
    const __bf16* __restrict__ Htg,               // [HEADS*FH][NN]
    const unsigned long long* __restrict__ adj_bits,
    const float* __restrict__ s1_all, const float* __restrict__ BD,
    const float* __restrict__ s2max_all, const float* __restrict__ ab_all,
    __bf16* __restrict__ accp,                    // C-native partials
    float* __restrict__ lg)                       // [HEADS][JSPLIT][NN]
{
    constexpr int NJT  = NN / 64 / JSPLIT;
    constexpr int NT   = FH / 16;
    constexpr int MEMB = NN / (WAVES * 32);       // row-blocks per group
    const int bid = blockIdx.x;
    const int e = bid & 7, qq = bid >> 3;
    const int gg = qq / MEMB, m = qq % MEMB;
    const int g = gg * 8 + e;                     // group id; g%8==bid%8 -> same XCD
    const int head = g % HEADS, js = g / HEADS;
    const int row0 = m * (WAVES * 32);
    const int jt0 = js * NJT;
    const int tid = threadIdx.x;
    const int w = tid >> 6, l = tid & 63, o = l >> 4, rl = l & 15;
    const int rbase = row0 + w * 32;

    __shared__ __attribute__((aligned(16))) __bf16 hbuf[2][FH * 64];

    const float* Bv = BD + (size_t)head * 2 * NN;
    const float* Dv = Bv + NN;
    const __bf16* hg = Htg + (size_t)head * FH * NN;
    const float smax = s2max_all[head];
    const float abh = ab_all[head];

    float Au[2], Cu[2];
    f32x2 lacc2[2] = {};
#pragma unroll
    for (int mt = 0; mt < 2; mt++) {
        int row = rbase + mt * 16 + rl;
        float z = s1_all[(size_t)head * NN + row] + abh + smax;
        float mr = fmaxf(z, 0.2f * z);
        Au[mt] = __expf(z - mr);
        Cu[mt] = __expf(0.2f * z - mr);
    }
    const unsigned long long* awp0 = adj_bits + (size_t)(rbase + rl) * 64 + jt0;
    const unsigned long long* awp1 = adj_bits + (size_t)(rbase + 16 + rl) * 64 + jt0;
    unsigned long long awc0 = awp0[0], awc1 = awp1[0];
    unsigned long long awn0 = 0, awn1 = 0;
    f32x4 acc[2][NT] = {};

    stage_tile<FH, WAVES * 64>(hg + (size_t)jt0 * 64, &hbuf[0][0], tid);

    for (int jl = 0; jl < NJT; jl++) {
        const int b = jl & 1;
        const int jt = jt0 + jl;
        // ---- produce A-frags (P) in registers, packed fp32 ----
        bf16x8 af[2][2];
#pragma unroll
        for (int kt = 0; kt < 2; kt++) {
            int jb = jt * 64 + kt * 32 + o * 8;
            f32x4 bv0 = *(const f32x4*)(Bv + jb), bv1 = *(const f32x4*)(Bv + jb + 4);
            f32x4 dv0 = *(const f32x4*)(Dv + jb), dv1 = *(const f32x4*)(Dv + jb + 4);
            unsigned int mb0 = (unsigned int)(awc0 >> ((kt * 4 + o) * 8)) & 0xFFu;
            unsigned int mb1 = (unsigned int)(awc1 >> ((kt * 4 + o) * 8)) & 0xFFu;
#pragma unroll
            for (int half = 0; half < 2; half++) {
                f32x4 bb = half ? bv1 : bv0;
                f32x4 dd = half ? dv1 : dv0;
#pragma unroll
                for (int pp = 0; pp < 2; pp++) {
                    const int q0 = half * 4 + pp * 2;
                    f32x2 bq = { bb[pp * 2], bb[pp * 2 + 1] };
                    f32x2 dq = { dd[pp * 2], dd[pp * 2 + 1] };
#pragma unroll
                    for (int r = 0; r < 2; r++) {
                        f32x2 t1 = (r ? Au[1] : Au[0]) * bq;
                        f32x2 t2 = (r ? Cu[1] : Cu[0]) * dq;
                        f32x2 p = __builtin_elementwise_max(t1, t2);
                        unsigned int mb = r ? mb1 : mb0;
                        int k0 = (int)(mb << (31 - q0)) >> 31;   // sign-extend bit q0
                        int k1 = (int)(mb << (30 - q0)) >> 31;
                        p[0] = __int_as_float(__float_as_int(p[0]) & k0);
                        p[1] = __int_as_float(__float_as_int(p[1]) & k1);
                        lacc2[r] += p;
                        af[r][kt][q0]     = (__bf16)p[0];
                        af[r][kt][q0 + 1] = (__bf16)p[1];
                    }
                }
            }
        }
        if (jl + 1 < NJT) { awn0 = awp0[jl + 1]; awn1 = awp1[jl + 1]; }
        __syncthreads();   // drains DMA(jt); orders prev-iter hbuf reads before overwrite
        if (jl + 1 < NJT)
            stage_tile<FH, WAVES * 64>(hg + (size_t)(jt + 1) * 64, &hbuf[b ^ 1][0], tid);
        // ---- consume: B-frag once, feeds both m-tiles ----
#pragma unroll
        for (int kt = 0; kt < 2; kt++) {
#pragma unroll
            for (int nt = 0; nt < NT; nt++) {
                int f = nt * 16 + rl;
                int slot = (kt * 4 + o) ^ (f & 7);
                bf16x8 bfr = *(const bf16x8*)(&hbuf[b][(f * 8 + slot) * 8]);
                acc[0][nt] = __builtin_amdgcn_mfma_f32_16x16x32_bf16(af[0][kt], bfr, acc[0][nt], 0, 0, 0);
                acc[1][nt] = __builtin_amdgcn_mfma_f32_16x16x32_bf16(af[1][kt], bfr, acc[1][nt], 0, 0, 0);
            }
        }
        awc0 = awn0; awc1 = awn1;
    }
    // ---- epilogue: row-sum partials + C-native coalesced partial store ----
    float lacc[2] = { lacc2[0][0] + lacc2[0][1], lacc2[1][0] + lacc2[1][1] };
#pragma unroll
    for (int mt = 0; mt < 2; mt++) {
        lacc[mt] += __shfl_xor(lacc[mt], 16, 64);
        lacc[mt] += __shfl_xor(lacc[mt], 32, 64);
    }
    if (l < 16) {
        float* lgp = lg + ((size_t)head * JSPLIT + js) * NN + rbase;
        lgp[l] = lacc[0];
        lgp[16 + l] = lacc[1];
    }
    const int g32 = m * WAVES + w;
    size_t wbase = (((size_t)js * HEADS + head) * 128 + g32) * (size_t)(2 * NT * 256);
#pragma unroll
    for (int mt = 0; mt < 2; mt++)
#pragma unroll
        for (int nt = 0; nt < NT; nt++) {
            bf16x4 t;
#pragma unroll
            for (int r4 = 0; r4 < 4; r4++) t[r4] = (__bf16)acc[mt][nt][r4];
            *(bf16x4*)(accp + wbase + (size_t)(mt * NT + nt) * 256 + l * 4) = t;
        }
}

// ---------------- reduce j-split row sums -> reciprocal per (head,row) ----------------
__global__ void lsum_kernel(const float* __restrict__ lg, float* __restrict__ inv, int S) {
    int i = blockIdx.x * 256 + threadIdx.x;        // i = head*NN + row
    int head = i >> 12, row = i & (NN - 1);
    float s = 0.f;
    for (int j = 0; j < S; j++) s += lg[((size_t)head * S + j) * NN + row];
    inv[i] = s > 0.f ? 1.f / s : 0.f;
}

// ---------------- combine layer-1: sum js, normalize, elu -> bf16 [N][512] ----------------
// accp layout: [js][head(4)][g(128)][mt(2)][nt(8)][lane(64)][reg(4)]
__global__ void combine1_kernel(const __bf16* __restrict__ accp,
                                const float* __restrict__ inv1,
                                __bf16* __restrict__ outb) {
    int gid = blockIdx.x * 256 + threadIdx.x;      // per head: 128*2*8*64 = 131072
    int l = gid & 63, nt = (gid >> 6) & 7, mt = (gid >> 9) & 1, g = gid >> 10;
    int head = blockIdx.y;
    int o = l >> 4, rl = l & 15;
    const size_t stride_js = (size_t)4 * 128 * 2 * 8 * 256;
    size_t base = ((((size_t)head * 128 + g) * 2 + mt) * 8 + nt) * 256 + l * 4;
    float v[4] = {0.f, 0.f, 0.f, 0.f};
#pragma unroll
    for (int js = 0; js < 8; js++) {
        bf16x4 t = *(const bf16x4*)(accp + base + js * stride_js);
#pragma unroll
        for (int q = 0; q < 4; q++) v[q] += (float)t[q];
    }
    int row0 = g * 32 + mt * 16 + o * 4;
    int col = head * 128 + nt * 16 + rl;
#pragma unroll
    for (int q = 0; q < 4; q++) {
        float x = v[q] * inv1[head * NN + row0 + q];
        x = x > 0.f ? x : __expf(x) - 1.f;
        outb[(size_t)(row0 + q) * 512 + col] = (__bf16)x;
    }
}

// ---------------- combine layer-2 + elu + log_softmax -> out ----------------
// accp layout: [js][g(128)][mt(2)][nt(4)][lane(64)][reg(4)]; wave per row.
__global__ void combine2_kernel(const __bf16* __restrict__ accp,
                                const float* __restrict__ inv2,
                                float* __restrict__ out) {
    int row = blockIdx.x * 4 + (threadIdx.x >> 6);
    int lam = threadIdx.x & 63;
    int g = row >> 5, mt = (row >> 4) & 1, o = (row >> 2) & 3, r4 = row & 3;
    int nt = lam >> 4, rl = lam & 15;
    int l = o * 16 + rl;
    const size_t stride_js = (size_t)128 * 2 * 4 * 256;
    size_t base = (((size_t)g * 2 + mt) * 4 + nt) * 256 + (size_t)l * 4 + r4;
    float v = 0.f;
#pragma unroll
    for (int js = 0; js < 16; js++) v += (float)accp[base + js * stride_js];
    v *= inv2[row];
    v = v > 0.f ? v : __expf(v) - 1.f;
    float m = v;
#pragma unroll
    for (int off = 1; off < 64; off <<= 1) m = fmaxf(m, __shfl_xor(m, off, 64));
    float ex = __expf(v - m);
    float s = ex;
#pragma unroll
    for (int off = 1; off < 64; off <<= 1) s += __shfl_xor(s, off, 64);
    out[(size_t)row * 64 + lam] = v - m - __logf(s);
}

extern "C" void kernel_launch(void* const* d_in, const int* in_sizes, int n_in,
                              void* d_out, int out_size, void* d_ws, size_t ws_size,
                              hipStream_t stream) {
    const float* X    = (const float*)d_in[0];
    const int*   adj  = (const int*)d_in[1];
    const float* W_h  = (const float*)d_in[2];
    const float* b_h  = (const float*)d_in[3];
    const float* a1_h = (const float*)d_in[4];
    const float* a2_h = (const float*)d_in[5];
    const float* ab_h = (const float*)d_in[6];
    const float* W_o  = (const float*)d_in[7];
    const float* b_o  = (const float*)d_in[8];
    const float* a1_o = (const float*)d_in[9];
    const float* a2_o = (const float*)d_in[10];
    const float* ab_o = (const float*)d_in[11];
    float* out = (float*)d_out;

    char* ws = (char*)d_ws;
    auto alloc = [&](size_t bytes) {
        char* p = ws; ws += (bytes + 255) & ~(size_t)255; return p;
    };
    // NOTE ws budget: R7's 63.1 MB crashed (likely ws_size ~60 MiB; R6's 58.9 MB
    // passed). Aliased unions below bring this to ~50.5 MB.
    unsigned long long* adj_bits = (unsigned long long*)alloc((size_t)NN * 64 * 8); // 2 MB
    __bf16* Bt1    = (__bf16*)alloc((size_t)512 * 512 * 2);     // 512 KB
    float*  biasp  = (float*)alloc(512 * 4);
    __bf16* Bt2    = (__bf16*)alloc((size_t)64 * 512 * 2);      // 64 KB
    // union: Xb (bf16, steps 3-4) / h2p (fp32, steps 9-10) — both 4 MB, disjoint lifetimes
    char*   xbu    = alloc((size_t)4 * NN * 64 * 4);            // 4 MB
    __bf16* Xb     = (__bf16*)xbu;
    float*  h2p    = (float*)xbu;
    float*  s1h    = (float*)alloc((size_t)4 * NN * 4);         // |-- contiguous,
    float*  s2h    = (float*)alloc((size_t)4 * NN * 4);         // |   one memset
    float*  s1o    = (float*)alloc((size_t)NN * 4);             // (plain-stored)
    float*  s2o    = (float*)alloc((size_t)NN * 4);
    float*  s2maxh = (float*)alloc(4 * 4);
    float*  s2maxo = (float*)alloc(4);
    float*  BDh    = (float*)alloc((size_t)4 * 2 * NN * 4);     // 128 KB
    float*  BDo    = (float*)alloc((size_t)2 * NN * 4);         // 32 KB
    __bf16* Htg    = (__bf16*)alloc((size_t)512 * NN * 2);      // 4 MB
    // union: accp1 (steps 6-8, 32 MB) / accp2 (steps 12-14, 8 MB) — disjoint lifetimes
    __bf16* accpA  = (__bf16*)alloc((size_t)8 * 4 * 128 * 2 * 8 * 256 * 2);  // 32 MB
    __bf16* accp1  = accpA;
    __bf16* accp2  = accpA;
    float*  lg1    = (float*)alloc((size_t)32 * NN * 4);        // 512 KB
    float*  inv1   = (float*)alloc((size_t)4 * NN * 4);         // 64 KB
    __bf16* outhb  = (__bf16*)alloc((size_t)NN * 512 * 2);      // 4 MB
    __bf16* Ht2    = (__bf16*)alloc((size_t)64 * NN * 2);       // 512 KB
    float*  lg2    = (float*)alloc((size_t)16 * NN * 4);        // 256 KB
    float*  inv2   = (float*)alloc((size_t)NN * 4);             // 16 KB  (~50.5 MB)

    // 0. zero the atomic s1h/s2h accumulators
    hipMemsetAsync(s1h, 0, (size_t)8 * NN * 4, stream);
    // 1. adjacency -> bitmasks (single read of the 67 MB int32 matrix)
    pack_adj_kernel<<<(NN * 64) / 4, 256, 0, stream>>>(adj, adj_bits);
    // 2. prepack weights (bf16, [n][k])
    prepack_kernel<<<1024, 256, 0, stream>>>(W_h, b_h, W_o, Bt1, biasp, Bt2);
    // 3. X -> bf16
    cast_bf16_kernel<<<(NN * 512 / 4) / 256, 256, 0, stream>>>(X, Xb);
    // 4. layer-1 GEMM fused: Htg (transposed bf16) + s1h/s2h atomics
    gemm_fused_kernel<<<dim3(8, 64), 256, 0, stream>>>(
        Xb, Bt1, biasp, a1_h, a2_h, Htg, s1h, s2h, NN, 512, 512);
    // 5. s2max + Bv/Dv exp tables (layer 1, per head)
    attn_prep_kernel<<<4, 256, 0, stream>>>(s2h, s2maxh, BDh);
    // 6. attention layer 1 partials (4 heads x 8 js, XCD-swizzled 1D grid)
    attn_kernel<128, 8, 4, 4><<<1024, 256, 0, stream>>>(
        Htg, adj_bits, s1h, BDh, s2maxh, ab_h, accp1, lg1);
    // 7. per-row reciprocal sums (layer 1)
    lsum_kernel<<<(4 * NN) / 256, 256, 0, stream>>>(lg1, inv1, 8);
    // 8. combine -> elu -> bf16 concat features [N][512]
    combine1_kernel<<<dim3(512, 4), 256, 0, stream>>>(accp1, inv1, outhb);
    // 9. layer-2 GEMM split-K x4 -> fp32 partials (4x parallelism vs fused 64-block)
    gemm_slice_kernel<<<dim3(4, 64), 256, 0, stream>>>(outhb, Bt2, h2p, NN, 512);
    // 10. sum slices + bias -> Ht2 transposed bf16 + s1o/s2o dots
    s12t_kernel<<<64, 256, 0, stream>>>(h2p, b_o, a1_o, a2_o, Ht2, s1o, s2o);
    // 11. s2max + Bv/Dv exp tables (layer 2)
    attn_prep_kernel<<<1, 256, 0, stream>>>(s2o, s2maxo, BDo);
    // 12. attention layer 2 partials (16 js, XCD-swizzled; accp2 aliases accp1)
    attn_kernel<64, 16, 2, 1><<<1024, 128, 0, stream>>>(
        Ht2, adj_bits, s1o, BDo, s2maxo, ab_o, accp2, lg2);
    // 13. per-row reciprocal sums (layer 2)
    lsum_kernel<<<NN / 256, 256, 0, stream>>>(lg2, inv2, 16);
    // 14. combine + elu + log_softmax -> out
    combine2_kernel<<<NN / 4, 256, 0, stream>>>(accp2, inv2, out);
}